// Round 1
// baseline (202.514 us; speedup 1.0000x reference)
//
#include <hip/hip_runtime.h>

// YOLO loss: 5-scalar reduction over N*S*S cells.
// Inputs: pred [N,S,S,30] f32, target_boxes [N,S,S,4] f32,
//         target_cls [N,S,S,20] f32, has_object_map [N,S,S] (bool -> int32 assumed)
// Output: [total, reg, contain, no_obj, cls] / N  (5 floats)

#define SS 28
#define BLOCK 256

__global__ __launch_bounds__(BLOCK) void yolo_main(
    const float* __restrict__ pred,   // [cells, 30]
    const float* __restrict__ tbox,   // [cells, 4]
    const float* __restrict__ tcls,   // [cells, 20]
    const int*   __restrict__ mask,   // [cells]
    float4* __restrict__ block_part,  // [gridDim.x]
    int cells)
{
    int cell = blockIdx.x * BLOCK + threadIdx.x;

    float acc_cls = 0.f, acc_noobj = 0.f, acc_reg = 0.f, acc_cont = 0.f;

    if (cell < cells) {
        // ---- loads (vectorized) ----
        float pr[30];
        const float2* p2 = (const float2*)(pred + (size_t)cell * 30);  // 8B aligned always
        #pragma unroll
        for (int i = 0; i < 15; ++i) {
            float2 v = p2[i];
            pr[2 * i] = v.x; pr[2 * i + 1] = v.y;
        }
        float4 tb = ((const float4*)tbox)[cell];
        float tc[20];
        const float4* t4 = (const float4*)(tcls + (size_t)cell * 20);  // 16B aligned
        #pragma unroll
        for (int i = 0; i < 5; ++i) {
            float4 v = t4[i];
            tc[4 * i] = v.x; tc[4 * i + 1] = v.y; tc[4 * i + 2] = v.z; tc[4 * i + 3] = v.w;
        }
        bool m = mask[cell] != 0;
        float fm = m ? 1.f : 0.f;

        // ---- class loss ----
        float cls = 0.f;
        #pragma unroll
        for (int j = 0; j < 20; ++j) {
            float d = pr[10 + j] - tc[j];
            cls += d * d;
        }
        acc_cls = fm * cls;

        // ---- no-object loss (raw; *0.5 in finalize) ----
        acc_noobj = (1.f - fm) * (pr[4] * pr[4] + pr[9] * pr[9]);

        // ---- IOU, exact reference arithmetic ----
        const float invS = 1.f / 28.f;
        float txc = tb.x * invS, tyc = tb.y * invS;
        float t0 = txc - 0.5f * tb.z, t1 = tyc - 0.5f * tb.w;
        float t2 = txc + 0.5f * tb.z, t3 = tyc + 0.5f * tb.w;
        float ta = (t2 - t0) * (t3 - t1);

        // box 1
        float b1xc = pr[0] * invS, b1yc = pr[1] * invS;
        float a0 = b1xc - 0.5f * pr[2], a1 = b1yc - 0.5f * pr[3];
        float a2 = b1xc + 0.5f * pr[2], a3 = b1yc + 0.5f * pr[3];
        float wx = fmaxf(fminf(a2, t2) - fmaxf(a0, t0), 0.f);
        float wy = fmaxf(fminf(a3, t3) - fmaxf(a1, t1), 0.f);
        float inter = wx * wy;
        float area1 = (a2 - a0) * (a3 - a1);
        float den = area1 + ta - inter;
        float iou1 = inter / (den > 0.f ? den : 1.f);

        // box 2
        float b2xc = pr[5] * invS, b2yc = pr[6] * invS;
        float c0 = b2xc - 0.5f * pr[7], c1 = b2yc - 0.5f * pr[8];
        float c2 = b2xc + 0.5f * pr[7], c3 = b2yc + 0.5f * pr[8];
        wx = fmaxf(fminf(c2, t2) - fmaxf(c0, t0), 0.f);
        wy = fmaxf(fminf(c3, t3) - fmaxf(c1, t1), 0.f);
        inter = wx * wy;
        float area2 = (c2 - c0) * (c3 - c1);
        den = area2 + ta - inter;
        float iou2 = inter / (den > 0.f ? den : 1.f);

        bool take1 = iou1 > iou2;
        float best_iou = take1 ? iou1 : iou2;
        float bbx = take1 ? pr[0] : pr[5];
        float bby = take1 ? pr[1] : pr[6];
        float bbw = take1 ? pr[2] : pr[7];
        float bbh = take1 ? pr[3] : pr[8];
        float bbc = take1 ? pr[4] : pr[9];

        // ---- xy loss ----
        float dx = bbx - tb.x, dy = bby - tb.y;
        float xy = dx * dx + dy * dy;

        // ---- wh loss (replicate where(mask, v, 1.0) before sqrt) ----
        float wp = m ? bbw : 1.f, hp = m ? bbh : 1.f;
        float wt = m ? tb.z : 1.f, ht = m ? tb.w : 1.f;
        float dw = sqrtf(wp) - sqrtf(wt);
        float dh = sqrtf(hp) - sqrtf(ht);
        float wh = dw * dw + dh * dh;

        acc_reg = fm * (xy + wh);

        // ---- contain-object loss ----
        float dc = bbc - best_iou;
        acc_cont = fm * dc * dc;
    }

    // ---- wave reduction (64 lanes) ----
    float4 v = make_float4(acc_cls, acc_noobj, acc_reg, acc_cont);
    #pragma unroll
    for (int off = 32; off >= 1; off >>= 1) {
        v.x += __shfl_down(v.x, off, 64);
        v.y += __shfl_down(v.y, off, 64);
        v.z += __shfl_down(v.z, off, 64);
        v.w += __shfl_down(v.w, off, 64);
    }
    __shared__ float4 sred[BLOCK / 64];
    int lane = threadIdx.x & 63;
    int wave = threadIdx.x >> 6;
    if (lane == 0) sred[wave] = v;
    __syncthreads();
    if (threadIdx.x == 0) {
        float4 r = sred[0];
        #pragma unroll
        for (int w = 1; w < BLOCK / 64; ++w) {
            r.x += sred[w].x; r.y += sred[w].y; r.z += sred[w].z; r.w += sred[w].w;
        }
        block_part[blockIdx.x] = r;
    }
}

__global__ __launch_bounds__(BLOCK) void yolo_final(
    const float4* __restrict__ part, int nparts, float* __restrict__ out, float invN)
{
    float4 v = make_float4(0.f, 0.f, 0.f, 0.f);
    for (int i = threadIdx.x; i < nparts; i += BLOCK) {
        float4 p = part[i];
        v.x += p.x; v.y += p.y; v.z += p.z; v.w += p.w;
    }
    #pragma unroll
    for (int off = 32; off >= 1; off >>= 1) {
        v.x += __shfl_down(v.x, off, 64);
        v.y += __shfl_down(v.y, off, 64);
        v.z += __shfl_down(v.z, off, 64);
        v.w += __shfl_down(v.w, off, 64);
    }
    __shared__ float4 sred[BLOCK / 64];
    int lane = threadIdx.x & 63;
    int wave = threadIdx.x >> 6;
    if (lane == 0) sred[wave] = v;
    __syncthreads();
    if (threadIdx.x == 0) {
        float4 r = sred[0];
        #pragma unroll
        for (int w = 1; w < BLOCK / 64; ++w) {
            r.x += sred[w].x; r.y += sred[w].y; r.z += sred[w].z; r.w += sred[w].w;
        }
        float cls    = r.x;
        float no_obj = 0.5f * r.y;   // L_NOOBJ
        float reg    = 5.0f * r.z;   // L_COORD
        float cont   = r.w;
        float total  = cls + no_obj + cont + reg;
        out[0] = total  * invN;
        out[1] = reg    * invN;
        out[2] = cont   * invN;
        out[3] = no_obj * invN;
        out[4] = cls    * invN;
    }
}

extern "C" void kernel_launch(void* const* d_in, const int* in_sizes, int n_in,
                              void* d_out, int out_size, void* d_ws, size_t ws_size,
                              hipStream_t stream) {
    const float* pred = (const float*)d_in[0];
    const float* tbox = (const float*)d_in[1];
    const float* tcls = (const float*)d_in[2];
    const int*   mask = (const int*)d_in[3];
    float* out = (float*)d_out;

    int cells = in_sizes[0] / 30;                 // N*S*S
    int n_img = cells / (SS * SS);                // N
    int nblocks = (cells + BLOCK - 1) / BLOCK;

    float4* part = (float4*)d_ws;                 // nblocks * 16 bytes

    yolo_main<<<nblocks, BLOCK, 0, stream>>>(pred, tbox, tcls, mask, part, cells);
    yolo_final<<<1, BLOCK, 0, stream>>>(part, nblocks, out, 1.0f / (float)n_img);
}